// Round 1
// 124.357 us; speedup vs baseline: 1.0760x; 1.0760x over previous
//
#include <hip/hip_runtime.h>

#define M_DIM 512
#define N_DIM 4096
#define K_DIM 4096
#define KB    (K_DIM / 2)   // bytes per row, fp4-packed

typedef __attribute__((ext_vector_type(4))) float f32x4;
typedef __attribute__((ext_vector_type(8))) int i32x8;
typedef __attribute__((ext_vector_type(4))) int i32x4;

// ---- ws layout (bytes) ----
// [0,1024)      float part_x[256]
// [1024,5120)   float part_w[1024]
// [5120,5128)   float amax_final[2]
// [8192, +1MB)  xq fp4 packed (512 x 2048 B)
// [then, +8MB)  wq fp4 packed (4096 x 2048 B)
#define PART_X_OFF 0
#define PART_X_N   256
#define PART_W_OFF 256
#define PART_W_N   1024
#define AMAX_OFF   1280
#define XQ_BYTE_OFF 8192
#define WQ_BYTE_OFF (XQ_BYTE_OFF + M_DIM * KB)

// ---------------------------------------------------------------- amax ------
__global__ __launch_bounds__(256) void amax_kernel(
    const float4* __restrict__ x4, const float4* __restrict__ w4,
    float* __restrict__ ws_f) {
    const int b = blockIdx.x;
    float m = 0.0f;
    if (b < PART_X_N) {  // x: 256 blocks
        const int n4 = M_DIM * K_DIM / 4, stride = PART_X_N * 256;
        for (int i = b * 256 + threadIdx.x; i < n4; i += stride) {
            float4 a = x4[i];
            m = fmaxf(m, fmaxf(fmaxf(fabsf(a.x), fabsf(a.y)),
                               fmaxf(fabsf(a.z), fabsf(a.w))));
        }
    } else {             // w: 1024 blocks
        const int n4 = N_DIM * K_DIM / 4, stride = PART_W_N * 256;
        for (int i = (b - PART_X_N) * 256 + threadIdx.x; i < n4; i += stride) {
            float4 a = w4[i];
            m = fmaxf(m, fmaxf(fmaxf(fabsf(a.x), fabsf(a.y)),
                               fmaxf(fabsf(a.z), fabsf(a.w))));
        }
    }
    for (int off = 32; off > 0; off >>= 1)
        m = fmaxf(m, __shfl_down(m, off, 64));
    __shared__ float sm[4];
    if ((threadIdx.x & 63) == 0) sm[threadIdx.x >> 6] = m;
    __syncthreads();
    if (threadIdx.x == 0) {
        m = fmaxf(fmaxf(sm[0], sm[1]), fmaxf(sm[2], sm[3]));
        ws_f[(b < PART_X_N) ? (PART_X_OFF + b) : (PART_W_OFF + b - PART_X_N)] = m;
    }
}

// ------------------------------------------------------------- quantize -----
// e2m1 nibble code: 0..7 -> {0,0.5,1,1.5,2,3,4,6}, bit3 = sign.
// Midpoint ties -> smaller magnitude (matches jnp.argmin first-occurrence).
__device__ __forceinline__ unsigned int q1n(float x, float s) {
    float a = fabsf(x) * s;
    unsigned int c;
    if      (a <= 0.25f) c = 0u;  // 0.0
    else if (a <= 0.75f) c = 1u;  // 0.5
    else if (a <= 1.25f) c = 2u;  // 1.0
    else if (a <= 1.75f) c = 3u;  // 1.5
    else if (a <= 2.5f)  c = 4u;  // 2.0
    else if (a <= 3.5f)  c = 5u;  // 3.0
    else if (a <= 5.0f)  c = 6u;  // 4.0
    else                 c = 7u;  // 6.0 (also handles clip)
    return c | ((__float_as_uint(x) >> 28) & 0x8u);
}
// 8 floats -> 8 nibbles, little-nibble order (element i at bits [4i+3:4i])
__device__ __forceinline__ unsigned int qpack8(float4 v0, float4 v1, float s) {
    return  q1n(v0.x, s)        | (q1n(v0.y, s) << 4)  |
           (q1n(v0.z, s) << 8)  | (q1n(v0.w, s) << 12) |
           (q1n(v1.x, s) << 16) | (q1n(v1.y, s) << 20) |
           (q1n(v1.z, s) << 24) | (q1n(v1.w, s) << 28);
}

__global__ __launch_bounds__(256) void quant_kernel(
    const float4* __restrict__ x4, const float4* __restrict__ w4,
    float* __restrict__ ws_f, unsigned char* __restrict__ ws_b) {
    const int b = blockIdx.x, t = threadIdx.x;
    const bool is_x = b < 512;
    float m = 0.0f;
    if (is_x) {
        m = ws_f[PART_X_OFF + t];
    } else {
        for (int i = t; i < PART_W_N; i += 256)
            m = fmaxf(m, ws_f[PART_W_OFF + i]);
    }
    for (int off = 32; off > 0; off >>= 1)
        m = fmaxf(m, __shfl_down(m, off, 64));
    __shared__ float sm[4];
    if ((t & 63) == 0) sm[t >> 6] = m;
    __syncthreads();
    m = fmaxf(fmaxf(sm[0], sm[1]), fmaxf(sm[2], sm[3]));
    float amax = fmaxf(m, 1e-12f);
    float s = 6.0f / amax;
    if (t == 0 && b == 0)   ws_f[AMAX_OFF + 0] = amax;
    if (t == 0 && b == 512) ws_f[AMAX_OFF + 1] = amax;

    const float4* src = is_x ? x4 : w4;
    unsigned char* dstb = ws_b + (is_x ? XQ_BYTE_OFF : WQ_BYTE_OFF);
    const int idx = (is_x ? b : b - 512) * 256 + t;   // 16 elements / thread
    const float4* p = src + (size_t)idx * 4;
    uint2 o;
    o.x = qpack8(p[0], p[1], s);
    o.y = qpack8(p[2], p[3], s);
    ((uint2*)dstb)[idx] = o;
}

// ----------------------------------------------------------------- GEMM -----
__device__ __forceinline__ void async_copy16(const void* g, void* l) {
    __builtin_amdgcn_global_load_lds(
        (const __attribute__((address_space(1))) unsigned int*)g,
        (__attribute__((address_space(3))) unsigned int*)l, 16, 0, 0);
}

// fp4 fragment: 32 elements = 16 B = one b128 from the XOR-swizzled chunk.
// 16x16x128 f8f6f4/fp4 uses only regs [0:3] of the 8-reg operand.
__device__ __forceinline__ i32x8 frag4(const unsigned char* rowbase,
                                       int mask, int l) {
    const i32x4 lo = *(const i32x4*)(rowbase + ((l ^ mask) * 16));
    const i32x4 z  = {0, 0, 0, 0};
    return __builtin_shufflevector(lo, z, 0, 1, 2, 3, 4, 5, 6, 7);
}

// C[m,n] = sum_k A[m,k]*B[n,k], fp4 operands (e2m1 codebook units).
// 64x64 tile, 512 blocks = 2/CU, 4 waves 2x2, BK=512 elements (256 B/row).
// Double-buffered LDS (2 x (16K A + 16K B) = 64 KB) with counted vmcnt(8):
// next-stage global_load_lds stays in flight across the compute phase
// (T3/T4 minimum 2-phase; raw s_barrier, never __syncthreads in the loop).
// LDS swizzle: physical chunk (row, pcol) holds global chunk pcol^(row&15),
// staged via pre-swizzled global source (linear LDS dest, rule #21).
__global__ __launch_bounds__(256, 2) void gemm_kernel(
    const unsigned char* __restrict__ A, const unsigned char* __restrict__ B,
    float* __restrict__ C, const float* __restrict__ amax2) {
    __shared__ __align__(16) unsigned char As[2][64 * 256];
    __shared__ __align__(16) unsigned char Bs[2][64 * 256];

    const int bid  = blockIdx.x;
    // bid = mt*64 + g*8 + x : x = XCD slice (N), g = n-subtile, mt = m-tile
    const int bm   = (bid >> 6) * 64;
    const int bn   = ((bid & 7) * 8 + ((bid >> 3) & 7)) * 64;
    const int tid  = threadIdx.x;
    const int lane = tid & 63;
    const int wave = tid >> 6;
    const int wm   = (wave >> 1) * 32;
    const int wn   = (wave & 1) * 32;
    const int t15  = lane & 15;
    const int quad = lane >> 4;

    const float cs = (1.0f / (6.0f / fmaxf(amax2[0], 1e-12f))) *
                     (1.0f / (6.0f / fmaxf(amax2[1], 1e-12f)));

    // staging: chunk c = j*256 + tid, LDS byte c*16 (wave-uniform base +
    // lane*16). Physical slot (row=c>>4, pcol=c&15) holds global 16B-chunk
    // gk = pcol ^ (row&15) of that row's current 256-B k-slice.
    const unsigned char* agp[4];
    const unsigned char* bgp[4];
#pragma unroll
    for (int j = 0; j < 4; j++) {
        const int c = j * 256 + tid;
        const int row = c >> 4, pcol = c & 15;
        const int gk = pcol ^ (row & 15);
        agp[j] = A + (size_t)(bm + row) * KB + gk * 16;
        bgp[j] = B + (size_t)(bn + row) * KB + gk * 16;
    }

#define STAGE(buf, kb)                                                  \
    do {                                                                \
        _Pragma("unroll")                                               \
        for (int j = 0; j < 4; j++) {                                   \
            async_copy16(agp[j] + (kb), &As[buf][(j * 256 + tid) * 16]);\
            async_copy16(bgp[j] + (kb), &Bs[buf][(j * 256 + tid) * 16]);\
        }                                                               \
    } while (0)

    f32x4 acc[2][2] = {};

    STAGE(0, 0);                               // prologue: stage 0 in flight
#pragma unroll 2
    for (int t = 0; t < 8; ++t) {
        const int cur = t & 1;
        if (t < 7) {
            STAGE(cur ^ 1, (t + 1) * 256);     // issue next stage first (8 VM)
            asm volatile("s_waitcnt vmcnt(8)" ::: "memory");  // cur loads done
        } else {
            asm volatile("s_waitcnt vmcnt(0)" ::: "memory");
        }
        __builtin_amdgcn_s_barrier();

        const unsigned char* A0 = As[cur] + (wm + t15) * 256;
        const unsigned char* A1 = A0 + 16 * 256;
        const unsigned char* B0 = Bs[cur] + (wn + t15) * 256;
        const unsigned char* B1 = B0 + 16 * 256;
#pragma unroll
        for (int s = 0; s < 4; ++s) {          // 4 x K=128 per stage
            const int l0 = s * 4 + quad;       // logical 16B-chunk index
            const i32x8 af0 = frag4(A0, t15, l0);
            const i32x8 af1 = frag4(A1, t15, l0);
            const i32x8 bf0 = frag4(B0, t15, l0);
            const i32x8 bf1 = frag4(B1, t15, l0);
            acc[0][0] = __builtin_amdgcn_mfma_scale_f32_16x16x128_f8f6f4(
                af0, bf0, acc[0][0], 4, 4, 0, 0x7F7F7F7F, 0, 0x7F7F7F7F);
            acc[0][1] = __builtin_amdgcn_mfma_scale_f32_16x16x128_f8f6f4(
                af0, bf1, acc[0][1], 4, 4, 0, 0x7F7F7F7F, 0, 0x7F7F7F7F);
            acc[1][0] = __builtin_amdgcn_mfma_scale_f32_16x16x128_f8f6f4(
                af1, bf0, acc[1][0], 4, 4, 0, 0x7F7F7F7F, 0, 0x7F7F7F7F);
            acc[1][1] = __builtin_amdgcn_mfma_scale_f32_16x16x128_f8f6f4(
                af1, bf1, acc[1][1], 4, 4, 0, 0x7F7F7F7F, 0, 0x7F7F7F7F);
        }
        __builtin_amdgcn_s_barrier();          // guard buf overwrite at t+1
    }
#undef STAGE

    // C/D layout (16x16): col = lane&15 (n), row = quad*4 + reg (m).
#pragma unroll
    for (int i = 0; i < 2; i++)
#pragma unroll
        for (int j = 0; j < 2; j++) {
            const int m0 = bm + wm + i * 16 + quad * 4;
            const int n0 = bn + wn + j * 16 + t15;
#pragma unroll
            for (int r = 0; r < 4; r++)
                C[(size_t)(m0 + r) * N_DIM + n0] = acc[i][j][r] * cs;
        }
}

// ---------------------------------------------------------------- launch ----
extern "C" void kernel_launch(void* const* d_in, const int* in_sizes, int n_in,
                              void* d_out, int out_size, void* d_ws, size_t ws_size,
                              hipStream_t stream) {
    const float* x = (const float*)d_in[0];   // [512, 4096]
    const float* w = (const float*)d_in[1];   // [4096, 4096]
    float* out = (float*)d_out;               // [512, 4096]

    float* ws_f = (float*)d_ws;
    unsigned char* ws_b = (unsigned char*)d_ws;
    const unsigned char* xq = ws_b + XQ_BYTE_OFF;
    const unsigned char* wq = ws_b + WQ_BYTE_OFF;

    amax_kernel<<<PART_X_N + PART_W_N, 256, 0, stream>>>(
        (const float4*)x, (const float4*)w, ws_f);
    quant_kernel<<<512 + 4096, 256, 0, stream>>>(
        (const float4*)x, (const float4*)w, ws_f, ws_b);
    gemm_kernel<<<(M_DIM / 64) * (N_DIM / 64), 256, 0, stream>>>(
        xq, wq, out, ws_f + AMAX_OFF);
}